// Round 3
// baseline (205.771 us; speedup 1.0000x reference)
//
#include <hip/hip_runtime.h>

// GTConv autoencoder on the product graph, MI355X.
// S = It (x) Ag + St (x) Bg, Ag = s00 I + s01 Sg, Bg = s10 I + s11 Sg (commute).
// => S^k x [t] = sum_{d,p<=k} c[k][d][p] * Sg^p x[t-d]  (cyclic in t).
// Conv: Y[t,m,o] = sum_i sum_{d,p} g[o,i,d,p] * Zp[t-d, i, m],
//   g[o,i,d,p] = sum_k h[o,i,k] c[k][d][p],  Z0 = x, Z1 = Sg x, Z2 = Sg^2 x.
// Fusion: block producing conv outputs (tq, o-chunk) also computes next-layer
// Z1/Z2 for exactly those (time, channel) slices from LDS => 6 kernels total.
//
// ws layout (floats):
//   SgTp  @ 0       (36864)  Sg^T packed [n/4][m][4] (float4 per column-quad)
//   Sg2Tp @ 36864   (36864)  (Sg^2)^T packed
//   g_e1  @ 73728 (144) g_e2 @ 73872 (4608) g_d1 @ 78480 (4608) g_d2 @ 83088 (144)
//   Za1 @ 83232  Za2 @ 181536  Zb1 @ 279840  Zb2 @ 378144   (98304 each)
//   buf1 @ 476448 (49152)  buf2 @ 525600 (49152)  buf3 = buf1 (dead after fused2)

#define NODES 192

__device__ __forceinline__ void compute_c(const float* __restrict__ s, float c[3][3][3]) {
    const float s00 = s[0], s01 = s[1], s10 = s[2], s11 = s[3];
    #pragma unroll
    for (int k = 0; k < 3; ++k)
        #pragma unroll
        for (int d = 0; d < 3; ++d)
            #pragma unroll
            for (int p = 0; p < 3; ++p) c[k][d][p] = 0.f;
    c[0][0][0] = 1.f;
    c[1][0][0] = s00; c[1][0][1] = s01;
    c[1][1][0] = s10; c[1][1][1] = s11;
    c[2][0][0] = s00 * s00;       c[2][0][1] = 2.f * s00 * s01;               c[2][0][2] = s01 * s01;
    c[2][1][0] = 2.f * s00 * s10; c[2][1][1] = 2.f * (s00 * s11 + s01 * s10); c[2][1][2] = 2.f * s01 * s11;
    c[2][2][0] = s10 * s10;       c[2][2][1] = 2.f * s10 * s11;               c[2][2][2] = s11 * s11;
}

// a1[i] = sum_n SgT[n][m] * xs[i*192+n]; a2[i] same with Sg2T.
// Packed layout: Ap[j*192+m] = float4 of rows 4j..4j+3, column m.
template <int IB>
__device__ __forceinline__ void gemv2p(const float4* __restrict__ Ap,
                                       const float4* __restrict__ Bp,
                                       const float* __restrict__ xs,
                                       int m, float* __restrict__ a1, float* __restrict__ a2) {
    #pragma unroll
    for (int i = 0; i < IB; ++i) { a1[i] = 0.f; a2[i] = 0.f; }
    #pragma unroll 4
    for (int j = 0; j < NODES / 4; ++j) {
        const float4 va = Ap[j * NODES + m];
        const float4 vb = Bp[j * NODES + m];
        #pragma unroll
        for (int i = 0; i < IB; ++i) {
            const float* x = xs + i * NODES + 4 * j;
            a1[i] += va.x * x[0] + va.y * x[1] + va.z * x[2] + va.w * x[3];
            a2[i] += vb.x * x[0] + vb.y * x[1] + vb.z * x[2] + vb.w * x[3];
        }
    }
}

// Prep: packed Sg^T (blocks 0..191), packed (Sg^2)^T straight from Sg (192..383),
// g tables (384). All parts independent.
__global__ __launch_bounds__(192) void prep_kernel(
        const float* __restrict__ Sg, const float* __restrict__ s,
        const float* __restrict__ he1, const float* __restrict__ he2,
        const float* __restrict__ hd1, const float* __restrict__ hd2,
        float* __restrict__ ws) {
    const int b = blockIdx.x, tid = threadIdx.x;
    float* SgTp  = ws;
    float* Sg2Tp = ws + 36864;
    if (b < 192) {                        // SgTp[(n>>2)*768 + m*4 + (n&3)] = Sg[m][n]
        const int mm = b, n = tid;
        SgTp[(n >> 2) * 768 + mm * 4 + (n & 3)] = Sg[mm * NODES + n];
    } else if (b < 384) {                 // Sg^2[m][n] = sum_r Sg[m][r] Sg[r][n]
        const int mm = b - 192, n = tid;
        __shared__ float row[NODES];
        row[tid] = Sg[mm * NODES + tid];
        __syncthreads();
        float acc = 0.f;
        #pragma unroll 4
        for (int r0 = 0; r0 < NODES; r0 += 8) {
            float v[8];
            #pragma unroll
            for (int u = 0; u < 8; ++u) v[u] = Sg[(r0 + u) * NODES + n];  // coalesced over n
            #pragma unroll
            for (int u = 0; u < 8; ++u) acc += row[r0 + u] * v[u];
        }
        Sg2Tp[(n >> 2) * 768 + mm * 4 + (n & 3)] = acc;
    } else {                              // g tables
        float c[3][3][3];
        compute_c(s, c);
        float* g = ws + 73728;
        const float* hs[4] = {he1, he2, hd1, hd2};
        const int cin[4]  = {1, 16, 32, 16};
        const int cout[4] = {16, 32, 16, 1};
        int base = 0;
        for (int l = 0; l < 4; ++l) {
            const int sz = cout[l] * cin[l] * 9;
            for (int idx = tid; idx < sz; idx += 192) {
                int o = idx / (cin[l] * 9);
                int rem = idx % (cin[l] * 9);
                int i = rem / 9, dp = rem % 9, d = dp / 3, p = dp % 3;
                float acc = 0.f;
                for (int k = 0; k < 3; ++k)
                    acc += hs[l][(o * cin[l] + i) * 3 + k] * c[k][d][p];
                g[base + idx] = acc;
            }
            base += sz;
        }
    }
}

// Layer-input reader at (time t, channel i, node n).
// INMODE 0: X (192x32 row-major), i==0. 1: plain [t][i][n]. 2: relu(zero-stuff up).
template <int CIN, int INMODE>
__device__ __forceinline__ float read_in(const float* __restrict__ src, int t, int i, int n) {
    if (INMODE == 0) return src[n * 32 + t];
    if (INMODE == 1) return src[(t * CIN + i) * NODES + n];
    if (t & 1) return 0.f;
    return fmaxf(src[((t >> 1) * CIN + i) * NODES + n], 0.f);
}

// Z for layer 1 input (X): Za1/Za2 at [t][0][m].
__global__ __launch_bounds__(192) void zker1(
        const float* __restrict__ X,
        const float4* __restrict__ Ap, const float4* __restrict__ Bp,
        float* __restrict__ Z1, float* __restrict__ Z2) {
    const int t = blockIdx.x, m = threadIdx.x;
    __shared__ float xs[NODES];
    xs[m] = X[m * 32 + t];
    __syncthreads();
    float a1[1], a2[1];
    gemv2p<1>(Ap, Bp, xs, m, a1, a2);
    Z1[t * NODES + m] = a1[0];
    Z2[t * NODES + m] = a2[0];
}

// Fused: conv for (tq, OB channels) [+down/max/relu or raw+relu] -> bufout,
// then next-layer Z1/Z2 for those channels from the activated values in LDS.
// DOWN: encoder pool-2; UP: next layer reads zero-stuffed upsample (Z at 2tq, zeros at 2tq+1).
template <int TIN, int CIN, int COUT, int OB, int INMODE, int DOWN, int UP>
__global__ __launch_bounds__(192) void fused_ker(
        const float* __restrict__ src,
        const float* __restrict__ Z1p, const float* __restrict__ Z2p,
        const float* __restrict__ g,
        const float4* __restrict__ Ap, const float4* __restrict__ Bp,
        float* __restrict__ bufout,
        float* __restrict__ Z1n, float* __restrict__ Z2n) {
    const int TQ = DOWN ? TIN / 2 : TIN;
    const int tq = blockIdx.x % TQ;
    const int o0 = (blockIdx.x / TQ) * OB;
    const int m  = threadIdx.x;
    __shared__ float gs[OB * CIN * 9];
    __shared__ float xs[OB * NODES];
    for (int idx = m; idx < OB * CIN * 9; idx += NODES) gs[idx] = g[o0 * CIN * 9 + idx];
    __syncthreads();
    {
        float res[2][OB];
        const int nt = DOWN ? 2 : 1;
        for (int tt = 0; tt < nt; ++tt) {
            const int t = DOWN ? tq * 2 + tt : tq;
            float acc[OB];
            #pragma unroll
            for (int o = 0; o < OB; ++o) acc[o] = 0.f;
            #pragma unroll 2
            for (int i = 0; i < CIN; ++i) {
                float z[3][3];
                #pragma unroll
                for (int d = 0; d < 3; ++d) {
                    int td = t - d; if (td < 0) td += TIN;
                    z[d][0] = read_in<CIN, INMODE>(src, td, i, m);
                    z[d][1] = Z1p[(td * CIN + i) * NODES + m];
                    z[d][2] = Z2p[(td * CIN + i) * NODES + m];
                }
                #pragma unroll
                for (int o = 0; o < OB; ++o) {
                    float a = acc[o];
                    #pragma unroll
                    for (int d = 0; d < 3; ++d)
                        #pragma unroll
                        for (int p = 0; p < 3; ++p)
                            a += gs[(o * CIN + i) * 9 + d * 3 + p] * z[d][p];
                    acc[o] = a;
                }
            }
            #pragma unroll
            for (int o = 0; o < OB; ++o) res[tt][o] = acc[o];
        }
        #pragma unroll
        for (int o = 0; o < OB; ++o) {
            float v;
            if (DOWN) {               // store activated
                v = fmaxf(fmaxf(res[0][o], res[1][o]), 0.f);
                bufout[(tq * COUT + o0 + o) * NODES + m] = v;
            } else {                  // store raw, activate for next layer
                const float r = res[0][o];
                bufout[(tq * COUT + o0 + o) * NODES + m] = r;
                v = fmaxf(r, 0.f);
            }
            xs[o * NODES + m] = v;
        }
    }
    __syncthreads();
    float a1[OB], a2[OB];
    gemv2p<OB>(Ap, Bp, xs, m, a1, a2);
    const int t2 = UP ? 2 * tq : tq;
    #pragma unroll
    for (int o = 0; o < OB; ++o) {
        Z1n[(t2 * COUT + o0 + o) * NODES + m] = a1[o];
        Z2n[(t2 * COUT + o0 + o) * NODES + m] = a2[o];
    }
    if (UP) {
        #pragma unroll
        for (int o = 0; o < OB; ++o) {
            Z1n[((t2 + 1) * COUT + o0 + o) * NODES + m] = 0.f;
            Z2n[((t2 + 1) * COUT + o0 + o) * NODES + m] = 0.f;
        }
    }
}

// Final conv (d2): 16->1 at T=32, input relu(up(buf3)), out[m*32+t].
__global__ __launch_bounds__(192) void cker4(
        const float* __restrict__ src,
        const float* __restrict__ Z1, const float* __restrict__ Z2,
        const float* __restrict__ g, float* __restrict__ out) {
    const int t = blockIdx.x, m = threadIdx.x;
    __shared__ float gs[144];
    for (int idx = m; idx < 144; idx += 192) gs[idx] = g[idx];
    __syncthreads();
    float acc = 0.f;
    #pragma unroll 4
    for (int i = 0; i < 16; ++i) {
        float z[3][3];
        #pragma unroll
        for (int d = 0; d < 3; ++d) {
            int td = t - d; if (td < 0) td += 32;
            z[d][0] = read_in<16, 2>(src, td, i, m);
            z[d][1] = Z1[(td * 16 + i) * NODES + m];
            z[d][2] = Z2[(td * 16 + i) * NODES + m];
        }
        #pragma unroll
        for (int d = 0; d < 3; ++d)
            #pragma unroll
            for (int p = 0; p < 3; ++p)
                acc += gs[i * 9 + d * 3 + p] * z[d][p];
    }
    out[m * 32 + t] = acc;
}

extern "C" void kernel_launch(void* const* d_in, const int* in_sizes, int n_in,
                              void* d_out, int out_size, void* d_ws, size_t ws_size,
                              hipStream_t stream) {
    (void)in_sizes; (void)n_in; (void)out_size; (void)ws_size;
    const float* X   = (const float*)d_in[0];
    const float* Sg  = (const float*)d_in[1];
    const float* s   = (const float*)d_in[2];
    const float* he1 = (const float*)d_in[3];
    const float* he2 = (const float*)d_in[4];
    const float* hd1 = (const float*)d_in[5];
    const float* hd2 = (const float*)d_in[6];
    float* out = (float*)d_out;
    float* ws  = (float*)d_ws;

    const float4* Ap = (const float4*)(ws);           // SgTp
    const float4* Bp = (const float4*)(ws + 36864);   // Sg2Tp
    float* g_e1 = ws + 73728;
    float* g_e2 = ws + 73872;
    float* g_d1 = ws + 78480;
    float* g_d2 = ws + 83088;
    float* Za1  = ws + 83232;
    float* Za2  = ws + 181536;
    float* Zb1  = ws + 279840;
    float* Zb2  = ws + 378144;
    float* buf1 = ws + 476448;
    float* buf2 = ws + 525600;
    float* buf3 = ws + 476448;   // reuse buf1 (dead after fused2)

    prep_kernel<<<385, 192, 0, stream>>>(Sg, s, he1, he2, hd1, hd2, ws);
    zker1<<<32, 192, 0, stream>>>(X, Ap, Bp, Za1, Za2);
    // e1: conv(X) -> down+relu -> buf1; Z for L2 (no upsample)
    fused_ker<32, 1, 16, 8, 0, 1, 0><<<32, 192, 0, stream>>>(
        X, Za1, Za2, g_e1, Ap, Bp, buf1, Zb1, Zb2);
    // e2: conv(buf1) -> down+relu -> buf2; Z for L3 (upsampled times)
    fused_ker<16, 16, 32, 8, 1, 1, 1><<<32, 192, 0, stream>>>(
        buf1, Zb1, Zb2, g_e2, Ap, Bp, buf2, Za1, Za2);
    // d1: conv(relu(up(buf2))) -> raw buf3; Z for L4 (upsampled times, relu'd)
    fused_ker<16, 32, 16, 8, 2, 0, 1><<<32, 192, 0, stream>>>(
        buf2, Za1, Za2, g_d1, Ap, Bp, buf3, Zb1, Zb2);
    // d2: final conv -> out (N,T)
    cker4<<<32, 192, 0, stream>>>(buf3, Zb1, Zb2, g_d2, out);
}

// Round 5
// 136.542 us; speedup vs baseline: 1.5070x; 1.5070x over previous
//
#include <hip/hip_runtime.h>

// GTConv autoencoder on the product graph, MI355X.
// S = It (x) Ag + St (x) Bg, Ag = s00 I + s01 Sg, Bg = s10 I + s11 Sg (commute).
// => S^k x [t] = sum_{d,p<=k} c[k][d][p] * Sg^p x[t-d]  (cyclic in t).
// Conv: Y[t,m,o] = sum_i sum_{d,p} g[o,i,d,p] * Zp[t-d, i, m],
//   g[o,i,d,p] = sum_k h[o,i,k] c[k][d][p],  Z0 = x, Z1 = Sg x, Z2 = Sg^2 x.
//
// Round-4 structure (fix: serialized-load latency):
//  - all loads unconditional (mask-multiply for upsample zeros, &(T-1) for cyclic t)
//  - Z / activation layouts [t][m][i] (channel fastest) -> per-thread float4 loads,
//    chunk-of-8-channels register arrays: all loads issued before FMAs
//  - dual Sg-GEMV with explicit double-buffered float4 prefetch
//  - L1's Z computed in-register inside f1 (zker eliminated): 5 kernels
//
// ws layout (float offsets):
//   SgTp 0 (36864) | Sg2Tp 36864 (36864) | XT 73728 (6144)
//   GE1 79872 (192) | GE2 80064 (6144) | GD1 86208 (6144) | GD2 92352 (192)
//   ZA1 92544 | ZA2 190848 | ZB1 289152 | ZB2 387456  (98304 each)
//   B1 485760 (49152) | B2 534912 (49152) | B3 584064 (49152)   total 633216 fl

#define NODES 192
typedef float4 f4;

__device__ __forceinline__ void compute_c(const float* __restrict__ s, float c[3][3][3]) {
    const float s00 = s[0], s01 = s[1], s10 = s[2], s11 = s[3];
    #pragma unroll
    for (int k = 0; k < 3; ++k)
        #pragma unroll
        for (int d = 0; d < 3; ++d)
            #pragma unroll
            for (int p = 0; p < 3; ++p) c[k][d][p] = 0.f;
    c[0][0][0] = 1.f;
    c[1][0][0] = s00; c[1][0][1] = s01;
    c[1][1][0] = s10; c[1][1][1] = s11;
    c[2][0][0] = s00 * s00;       c[2][0][1] = 2.f * s00 * s01;               c[2][0][2] = s01 * s01;
    c[2][1][0] = 2.f * s00 * s10; c[2][1][1] = 2.f * (s00 * s11 + s01 * s10); c[2][1][2] = 2.f * s11 * s01;
    c[2][2][0] = s10 * s10;       c[2][2][1] = 2.f * s10 * s11;               c[2][2][2] = s11 * s11;
}

// Dual GEMV: a1[i] = sum_n Sg[m,n] xs[i*192+n], a2[i] same with Sg^2.
// Packed: Ap[j*192+m] = float4 {Sg[m][4j..4j+3]}. Double-buffered prefetch.
template <int IB>
__device__ __forceinline__ void gemv2(const f4* __restrict__ Ap, const f4* __restrict__ Bp,
                                      const float* __restrict__ xs, int m,
                                      float* __restrict__ a1, float* __restrict__ a2) {
    #pragma unroll
    for (int i = 0; i < IB; ++i) { a1[i] = 0.f; a2[i] = 0.f; }
    f4 va[4], vb[4], na[4], nb[4];
    #pragma unroll
    for (int u = 0; u < 4; ++u) { va[u] = Ap[u * NODES + m]; vb[u] = Bp[u * NODES + m]; }
    #pragma unroll 1
    for (int jc = 0; jc < 12; ++jc) {
        if (jc < 11) {
            #pragma unroll
            for (int u = 0; u < 4; ++u) {
                na[u] = Ap[((jc + 1) * 4 + u) * NODES + m];
                nb[u] = Bp[((jc + 1) * 4 + u) * NODES + m];
            }
        }
        #pragma unroll
        for (int u = 0; u < 4; ++u) {
            const float* x = xs + 4 * (jc * 4 + u);
            #pragma unroll
            for (int i = 0; i < IB; ++i) {
                const float* xi = x + i * NODES;
                a1[i] += va[u].x * xi[0] + va[u].y * xi[1] + va[u].z * xi[2] + va[u].w * xi[3];
                a2[i] += vb[u].x * xi[0] + vb[u].y * xi[1] + vb[u].z * xi[2] + vb[u].w * xi[3];
            }
        }
        if (jc < 11) {
            #pragma unroll
            for (int u = 0; u < 4; ++u) { va[u] = na[u]; vb[u] = nb[u]; }
        }
    }
}

// prep: b<192 pack SgT; b<384 Sg^2 rows -> packed; b==384 padded g tables; b==385 XT.
__global__ __launch_bounds__(192) void prep_kernel(
        const float* __restrict__ X, const float* __restrict__ Sg, const float* __restrict__ s,
        const float* __restrict__ he1, const float* __restrict__ he2,
        const float* __restrict__ hd1, const float* __restrict__ hd2,
        float* __restrict__ ws) {
    const int b = blockIdx.x, tid = threadIdx.x;
    float* SgTp  = ws;
    float* Sg2Tp = ws + 36864;
    float* XT    = ws + 73728;
    float* g     = ws + 79872;           // GE1 base; GE2/GD1/GD2 follow padded-12
    if (b < 192) {                        // SgTp[(n>>2)*768 + m*4 + (n&3)] = Sg[m][n]
        const int mm = b, n = tid;
        SgTp[(n >> 2) * 768 + mm * 4 + (n & 3)] = Sg[mm * NODES + n];
    } else if (b < 384) {                 // Sg^2[mm][n]
        const int mm = b - 192, n = tid;
        __shared__ float row[NODES];
        row[tid] = Sg[mm * NODES + tid];
        __syncthreads();
        float acc = 0.f;
        #pragma unroll 1
        for (int r0 = 0; r0 < NODES; r0 += 16) {
            float v[16];
            #pragma unroll
            for (int u = 0; u < 16; ++u) v[u] = Sg[(r0 + u) * NODES + n];  // coalesced over n
            #pragma unroll
            for (int u = 0; u < 16; ++u) acc += row[r0 + u] * v[u];
        }
        Sg2Tp[(n >> 2) * 768 + mm * 4 + (n & 3)] = acc;
    } else if (b == 384) {                // g tables, padded to 12 floats per (o,i)
        float c[3][3][3];
        compute_c(s, c);
        // pairs: e1 16 @g+0, e2 512 @g+192, d1 512 @g+6336, d2 16 @g+12480
        for (int w = tid; w < 1056; w += NODES) {
            const float* h; int gbase, pl;
            if (w < 16)        { h = he1; gbase = 0;     pl = w; }
            else if (w < 528)  { h = he2; gbase = 192;   pl = w - 16; }
            else if (w < 1040) { h = hd1; gbase = 6336;  pl = w - 528; }
            else               { h = hd2; gbase = 12480; pl = w - 1040; }
            const float h0 = h[pl * 3], h1 = h[pl * 3 + 1], h2 = h[pl * 3 + 2];
            float* gp = g + gbase + pl * 12;
            #pragma unroll
            for (int dp = 0; dp < 12; ++dp) {
                float val = 0.f;
                if (dp < 9) {
                    const int d = dp / 3, p = dp % 3;
                    val = h0 * c[0][d][p] + h1 * c[1][d][p] + h2 * c[2][d][p];
                }
                gp[dp] = val;
            }
        }
    } else {                              // XT[t*192+n] = X[n*32+t]
        const int n = tid;
        const f4* xr = (const f4*)(X + n * 32);
        f4 vv[8];
        #pragma unroll
        for (int q = 0; q < 8; ++q) vv[q] = xr[q];
        #pragma unroll
        for (int q = 0; q < 8; ++q) {
            XT[(4 * q + 0) * NODES + n] = vv[q].x;
            XT[(4 * q + 1) * NODES + n] = vv[q].y;
            XT[(4 * q + 2) * NODES + n] = vv[q].z;
            XT[(4 * q + 3) * NODES + n] = vv[q].w;
        }
    }
}

// f1 (e1): 1->16, T=32, down+relu -> B1[16][192][16]; Z(L2) -> ZB[16][192][16].
// L1's own Z computed in-register from LDS-staged X rows. grid 64 = 16 tq x 4 oc.
__global__ __launch_bounds__(192) void f1_ker(
        const float* __restrict__ XT, const f4* __restrict__ Ap, const f4* __restrict__ Bp,
        const float* __restrict__ ge1, float* __restrict__ B1,
        float* __restrict__ Zb1, float* __restrict__ Zb2) {
    const int tq = blockIdx.x & 15, o0 = (blockIdx.x >> 4) * 4, m = threadIdx.x;
    __shared__ __align__(16) float xls[4 * NODES];
    __shared__ __align__(16) float vls[4 * NODES];
    __shared__ __align__(16) float gls[48];
    #pragma unroll
    for (int dl = 0; dl < 4; ++dl) {
        const int u = (2 * tq + dl - 2) & 31;
        xls[dl * NODES + m] = XT[u * NODES + m];
    }
    if (m < 48) gls[m] = ge1[o0 * 12 + m];
    __syncthreads();
    float z1[4], z2[4];
    gemv2<4>(Ap, Bp, xls, m, z1, z2);        // Z1/Z2 at the 4 staged times
    float x0[4];
    #pragma unroll
    for (int dl = 0; dl < 4; ++dl) x0[dl] = xls[dl * NODES + m];
    float acc[2][4];
    #pragma unroll
    for (int o = 0; o < 4; ++o) {
        const float* gr = &gls[o * 12];
        const f4 ga = *(const f4*)gr, gb = *(const f4*)(gr + 4), gc = *(const f4*)(gr + 8);
        #pragma unroll
        for (int tt = 0; tt < 2; ++tt) {
            acc[tt][o] = ga.x * x0[tt + 2] + ga.y * z1[tt + 2] + ga.z * z2[tt + 2]
                       + ga.w * x0[tt + 1] + gb.x * z1[tt + 1] + gb.y * z2[tt + 1]
                       + gb.z * x0[tt]     + gb.w * z1[tt]     + gc.x * z2[tt];
        }
    }
    float v[4];
    #pragma unroll
    for (int o = 0; o < 4; ++o) { v[o] = fmaxf(fmaxf(acc[0][o], acc[1][o]), 0.f); vls[o * NODES + m] = v[o]; }
    *(f4*)(B1 + (tq * NODES + m) * 16 + o0) = make_float4(v[0], v[1], v[2], v[3]);
    __syncthreads();
    float a1[4], a2[4];
    gemv2<4>(Ap, Bp, vls, m, a1, a2);
    *(f4*)(Zb1 + (tq * NODES + m) * 16 + o0) = make_float4(a1[0], a1[1], a1[2], a1[3]);
    *(f4*)(Zb2 + (tq * NODES + m) * 16 + o0) = make_float4(a2[0], a2[1], a2[2], a2[3]);
}

// f2 (e2): 16->32, T=16, down+relu -> B2[8][192][32]; Z(L3, zero-stuffed T=16) -> ZA[16][192][32].
// grid 64 = 8 tq x 8 oc.
__global__ __launch_bounds__(192) void f2_ker(
        const float* __restrict__ B1, const f4* __restrict__ Ap, const f4* __restrict__ Bp,
        const float* __restrict__ Zb1, const float* __restrict__ Zb2,
        const float* __restrict__ ge2, float* __restrict__ B2,
        float* __restrict__ Za1, float* __restrict__ Za2) {
    const int tq = blockIdx.x & 7, o0 = (blockIdx.x >> 3) * 4, m = threadIdx.x;
    __shared__ __align__(16) float gls[4 * 16 * 12];
    __shared__ __align__(16) float vls[4 * NODES];
    for (int idx = m; idx < 768; idx += NODES) gls[idx] = ge2[o0 * 16 * 12 + idx];
    __syncthreads();
    float acc[2][4];
    #pragma unroll
    for (int tt = 0; tt < 2; ++tt)
        #pragma unroll
        for (int o = 0; o < 4; ++o) acc[tt][o] = 0.f;
    #pragma unroll 1
    for (int ic = 0; ic < 2; ++ic) {
        float z[4][3][8];
        #pragma unroll
        for (int dl = 0; dl < 4; ++dl) {
            const int u = (2 * tq + dl - 2) & 15;
            const int base = (u * NODES + m) * 16 + ic * 8;
            *(f4*)&z[dl][0][0] = *(const f4*)(B1 + base);
            *(f4*)&z[dl][0][4] = *(const f4*)(B1 + base + 4);
            *(f4*)&z[dl][1][0] = *(const f4*)(Zb1 + base);
            *(f4*)&z[dl][1][4] = *(const f4*)(Zb1 + base + 4);
            *(f4*)&z[dl][2][0] = *(const f4*)(Zb2 + base);
            *(f4*)&z[dl][2][4] = *(const f4*)(Zb2 + base + 4);
        }
        #pragma unroll
        for (int o = 0; o < 4; ++o)
            #pragma unroll
            for (int ch = 0; ch < 8; ++ch) {
                const int i = ic * 8 + ch;
                const float* gr = &gls[(o * 16 + i) * 12];
                const f4 ga = *(const f4*)gr, gb = *(const f4*)(gr + 4), gc = *(const f4*)(gr + 8);
                #pragma unroll
                for (int tt = 0; tt < 2; ++tt) {
                    acc[tt][o] += ga.x * z[tt + 2][0][ch] + ga.y * z[tt + 2][1][ch] + ga.z * z[tt + 2][2][ch]
                                + ga.w * z[tt + 1][0][ch] + gb.x * z[tt + 1][1][ch] + gb.y * z[tt + 1][2][ch]
                                + gb.z * z[tt][0][ch]     + gb.w * z[tt][1][ch]     + gc.x * z[tt][2][ch];
                }
            }
    }
    float v[4];
    #pragma unroll
    for (int o = 0; o < 4; ++o) { v[o] = fmaxf(fmaxf(acc[0][o], acc[1][o]), 0.f); vls[o * NODES + m] = v[o]; }
    *(f4*)(B2 + (tq * NODES + m) * 32 + o0) = make_float4(v[0], v[1], v[2], v[3]);
    __syncthreads();
    float a1[4], a2[4];
    gemv2<4>(Ap, Bp, vls, m, a1, a2);
    const int t2 = 2 * tq;
    *(f4*)(Za1 + (t2 * NODES + m) * 32 + o0) = make_float4(a1[0], a1[1], a1[2], a1[3]);
    *(f4*)(Za2 + (t2 * NODES + m) * 32 + o0) = make_float4(a2[0], a2[1], a2[2], a2[3]);
    const f4 zz = make_float4(0.f, 0.f, 0.f, 0.f);
    *(f4*)(Za1 + ((t2 + 1) * NODES + m) * 32 + o0) = zz;
    *(f4*)(Za2 + ((t2 + 1) * NODES + m) * 32 + o0) = zz;
}

// f3 (d1): 32->16, T=16, input relu(up(B2)) (mask), raw -> B3[16][192][16];
// Z(L4, zero-stuffed T=32) from relu(out) -> ZB[32][192][16]. grid 64 = 16 tq x 4 oc.
__global__ __launch_bounds__(192) void f3_ker(
        const float* __restrict__ B2, const f4* __restrict__ Ap, const f4* __restrict__ Bp,
        const float* __restrict__ Za1, const float* __restrict__ Za2,
        const float* __restrict__ gd1, float* __restrict__ B3,
        float* __restrict__ Zb1, float* __restrict__ Zb2) {
    const int tq = blockIdx.x & 15, o0 = (blockIdx.x >> 4) * 4, m = threadIdx.x;
    __shared__ __align__(16) float gls[4 * 32 * 12];
    __shared__ __align__(16) float vls[4 * NODES];
    for (int idx = m; idx < 1536; idx += NODES) gls[idx] = gd1[o0 * 32 * 12 + idx];
    __syncthreads();
    float acc[4];
    #pragma unroll
    for (int o = 0; o < 4; ++o) acc[o] = 0.f;
    #pragma unroll 1
    for (int ic = 0; ic < 4; ++ic) {
        float z[3][3][8];
        #pragma unroll
        for (int dl = 0; dl < 3; ++dl) {
            const int u = (tq + dl - 2) & 15;
            const float msk = (u & 1) ? 0.f : 1.f;
            const int sb = ((u >> 1) * NODES + m) * 32 + ic * 8;
            const int zb = (u * NODES + m) * 32 + ic * 8;
            const f4 p0 = *(const f4*)(B2 + sb), p1 = *(const f4*)(B2 + sb + 4);
            *(f4*)&z[dl][1][0] = *(const f4*)(Za1 + zb);
            *(f4*)&z[dl][1][4] = *(const f4*)(Za1 + zb + 4);
            *(f4*)&z[dl][2][0] = *(const f4*)(Za2 + zb);
            *(f4*)&z[dl][2][4] = *(const f4*)(Za2 + zb + 4);
            z[dl][0][0] = fmaxf(p0.x, 0.f) * msk;  z[dl][0][1] = fmaxf(p0.y, 0.f) * msk;
            z[dl][0][2] = fmaxf(p0.z, 0.f) * msk;  z[dl][0][3] = fmaxf(p0.w, 0.f) * msk;
            z[dl][0][4] = fmaxf(p1.x, 0.f) * msk;  z[dl][0][5] = fmaxf(p1.y, 0.f) * msk;
            z[dl][0][6] = fmaxf(p1.z, 0.f) * msk;  z[dl][0][7] = fmaxf(p1.w, 0.f) * msk;
        }
        #pragma unroll
        for (int o = 0; o < 4; ++o)
            #pragma unroll
            for (int ch = 0; ch < 8; ++ch) {
                const int i = ic * 8 + ch;
                const float* gr = &gls[(o * 32 + i) * 12];
                const f4 ga = *(const f4*)gr, gb = *(const f4*)(gr + 4), gc = *(const f4*)(gr + 8);
                acc[o] += ga.x * z[2][0][ch] + ga.y * z[2][1][ch] + ga.z * z[2][2][ch]   // d=0
                        + ga.w * z[1][0][ch] + gb.x * z[1][1][ch] + gb.y * z[1][2][ch]   // d=1
                        + gb.z * z[0][0][ch] + gb.w * z[0][1][ch] + gc.x * z[0][2][ch];  // d=2
            }
    }
    float v[4];
    #pragma unroll
    for (int o = 0; o < 4; ++o) { v[o] = fmaxf(acc[o], 0.f); vls[o * NODES + m] = v[o]; }
    *(f4*)(B3 + (tq * NODES + m) * 16 + o0) = make_float4(acc[0], acc[1], acc[2], acc[3]);  // raw
    __syncthreads();
    float a1[4], a2[4];
    gemv2<4>(Ap, Bp, vls, m, a1, a2);
    const int t2 = 2 * tq;
    *(f4*)(Zb1 + (t2 * NODES + m) * 16 + o0) = make_float4(a1[0], a1[1], a1[2], a1[3]);
    *(f4*)(Zb2 + (t2 * NODES + m) * 16 + o0) = make_float4(a2[0], a2[1], a2[2], a2[3]);
    const f4 zz = make_float4(0.f, 0.f, 0.f, 0.f);
    *(f4*)(Zb1 + ((t2 + 1) * NODES + m) * 16 + o0) = zz;
    *(f4*)(Zb2 + ((t2 + 1) * NODES + m) * 16 + o0) = zz;
}

// cker4 (d2): 16->1, T=32, input relu(up(B3)) (mask), out[m*32+t]. grid 32.
__global__ __launch_bounds__(192) void cker4(
        const float* __restrict__ B3,
        const float* __restrict__ Zb1, const float* __restrict__ Zb2,
        const float* __restrict__ gd2, float* __restrict__ out) {
    const int t = blockIdx.x, m = threadIdx.x;
    __shared__ __align__(16) float gls[16 * 12];
    for (int idx = m; idx < 192; idx += NODES) gls[idx] = gd2[idx];
    __syncthreads();
    float acc = 0.f;
    #pragma unroll 1
    for (int ic = 0; ic < 2; ++ic) {
        float z[3][3][8];
        #pragma unroll
        for (int dl = 0; dl < 3; ++dl) {
            const int u = (t + dl - 2) & 31;
            const float msk = (u & 1) ? 0.f : 1.f;
            const int sb = ((u >> 1) * NODES + m) * 16 + ic * 8;
            const int zb = (u * NODES + m) * 16 + ic * 8;
            const f4 p0 = *(const f4*)(B3 + sb), p1 = *(const f4*)(B3 + sb + 4);
            *(f4*)&z[dl][1][0] = *(const f4*)(Zb1 + zb);
            *(f4*)&z[dl][1][4] = *(const f4*)(Zb1 + zb + 4);
            *(f4*)&z[dl][2][0] = *(const f4*)(Zb2 + zb);
            *(f4*)&z[dl][2][4] = *(const f4*)(Zb2 + zb + 4);
            z[dl][0][0] = fmaxf(p0.x, 0.f) * msk;  z[dl][0][1] = fmaxf(p0.y, 0.f) * msk;
            z[dl][0][2] = fmaxf(p0.z, 0.f) * msk;  z[dl][0][3] = fmaxf(p0.w, 0.f) * msk;
            z[dl][0][4] = fmaxf(p1.x, 0.f) * msk;  z[dl][0][5] = fmaxf(p1.y, 0.f) * msk;
            z[dl][0][6] = fmaxf(p1.z, 0.f) * msk;  z[dl][0][7] = fmaxf(p1.w, 0.f) * msk;
        }
        #pragma unroll
        for (int ch = 0; ch < 8; ++ch) {
            const int i = ic * 8 + ch;
            const float* gr = &gls[i * 12];
            const f4 ga = *(const f4*)gr, gb = *(const f4*)(gr + 4), gc = *(const f4*)(gr + 8);
            acc += ga.x * z[2][0][ch] + ga.y * z[2][1][ch] + ga.z * z[2][2][ch]
                 + ga.w * z[1][0][ch] + gb.x * z[1][1][ch] + gb.y * z[1][2][ch]
                 + gb.z * z[0][0][ch] + gb.w * z[0][1][ch] + gc.x * z[0][2][ch];
        }
    }
    out[m * 32 + t] = acc;
}

extern "C" void kernel_launch(void* const* d_in, const int* in_sizes, int n_in,
                              void* d_out, int out_size, void* d_ws, size_t ws_size,
                              hipStream_t stream) {
    (void)in_sizes; (void)n_in; (void)out_size; (void)ws_size;
    const float* X   = (const float*)d_in[0];
    const float* Sg  = (const float*)d_in[1];
    const float* s   = (const float*)d_in[2];
    const float* he1 = (const float*)d_in[3];
    const float* he2 = (const float*)d_in[4];
    const float* hd1 = (const float*)d_in[5];
    const float* hd2 = (const float*)d_in[6];
    float* out = (float*)d_out;
    float* ws  = (float*)d_ws;

    const f4* Ap = (const f4*)(ws);            // SgTp
    const f4* Bp = (const f4*)(ws + 36864);    // Sg2Tp
    float* XT  = ws + 73728;
    float* GE1 = ws + 79872;
    float* GE2 = ws + 80064;
    float* GD1 = ws + 86208;
    float* GD2 = ws + 92352;
    float* ZA1 = ws + 92544;
    float* ZA2 = ws + 190848;
    float* ZB1 = ws + 289152;
    float* ZB2 = ws + 387456;
    float* B1  = ws + 485760;
    float* B2  = ws + 534912;
    float* B3  = ws + 584064;

    prep_kernel<<<386, 192, 0, stream>>>(X, Sg, s, he1, he2, hd1, hd2, ws);
    f1_ker<<<64, 192, 0, stream>>>(XT, Ap, Bp, GE1, B1, ZB1, ZB2);
    f2_ker<<<64, 192, 0, stream>>>(B1, Ap, Bp, ZB1, ZB2, GE2, B2, ZA1, ZA2);
    f3_ker<<<64, 192, 0, stream>>>(B2, Ap, Bp, ZA1, ZA2, GD1, B3, ZB1, ZB2);
    cker4<<<32, 192, 0, stream>>>(B3, ZB1, ZB2, GD2, out);
}